// Round 6
// baseline (233.112 us; speedup 1.0000x reference)
//
#include <hip/hip_runtime.h>
#include <math.h>

// InnerPatchSoftShiftTriple — v6: v5 with compile fix (named-register U fragments,
// direct "+v" pins). Pinned-register U, XCD-swizzled grid, pipelined slab/F
// prefetch, fused pre-pass and fused ks-reduction (2 kernels total).
//
// s[l,k] = sum_{bb,aa,c} lat[c][R(l,bb,aa)] * knorm[c][R(k,bb,aa)]
// R(m,bb,aa) = Tinv(T(m)+bb-1)+(aa-1), valid iff intermediate/final in [0,L)
// T(m)=Tinv(m)=((m&63)<<6)|(m>>6).  k swept as k=Tinv(k'), k' contiguous.
// garr[b][sg][aa][c] = knorm[Tinv(sg-1)+aa-1][c] (0 invalid), bytes within slot
// XOR-swizzled by ((sg&7)<<4) so LDS slab b128 reads spread across bank quads.

#define L 4096

typedef unsigned int   u32;
typedef unsigned short u16;
typedef short  short8 __attribute__((ext_vector_type(8)));
typedef float  f32x16 __attribute__((ext_vector_type(16)));

#define MFMA32(a,b,c) __builtin_amdgcn_mfma_f32_32x32x16_bf16((a),(b),(c),0,0,0)

__device__ __forceinline__ u16 f2bf(float f) {
    u32 u = __float_as_uint(f);
    return (u16)((u + 0x7FFFu + ((u >> 16) & 1u)) >> 16);
}
__device__ __forceinline__ void lds_async16(void* lds, const void* g) {
    __builtin_amdgcn_global_load_lds((const __attribute__((address_space(1))) u32*)g,
                                     (__attribute__((address_space(3))) u32*)lds, 16, 0, 0);
}

// ---- ws layout (bytes) ----
#define OFF_LATB  0u          // u16[2][4096][64] raw latter (transposed)
#define OFF_FORB  1048576u    // u16[2][4096][64] former (transposed)
#define OFF_GARR  2097152u    // 2 x 4104 slots x 384 B tripled swizzled knorm
#define GARR_BB   1575936u    // 4104*384
#define OFF_FBITS 5249024u    // u32[128]
#define OFF_ROWS  5249536u    // int[4096]
#define OFF_CNT   5265920u    // int
#define OFF_DONE  5266176u    // u32[2][64] fan-in counters
#define OFF_PART  5267200u    // [2][64][8] x (32 rows x 144B)  -> end 9,985,792

// ---------------- fused pre-pass ----------------
__global__ void k_pre1(const float4* __restrict__ x4, float4* __restrict__ out4,
                       const float* __restrict__ x, const float* __restrict__ mask,
                       u16* __restrict__ latb, u16* __restrict__ forb,
                       char* __restrict__ garr, int* __restrict__ rows,
                       int* __restrict__ cnt, u32* __restrict__ fbits,
                       u32* __restrict__ done)
{
    const int blk = blockIdx.x, t = threadIdx.x;
    if (blk < 1537) {                       // passthrough copy + zero shift
        int i = blk * 256 + t;
        if (i < 262144) {
            int b = i >> 17, j = i & 131071;
            out4[b * 196608 + j] = x4[b * 131072 + j];
        } else if (i < 393216) {
            int z = i - 262144; int b = z >> 16, j = z & 65535;
            out4[b * 196608 + 131072 + j] = make_float4(0.f, 0.f, 0.f, 0.f);
        }
    } else if (blk < 1569) {                // norm + pack + garr scatter
        int tid = (blk - 1537) * 256 + t;   // 8192
        int b = tid >> 12, l = tid & 4095;
        const float* xb = x + (size_t)b * 524288;
        float v[64]; float ss = 0.f;
        #pragma unroll
        for (int c = 0; c < 64; ++c) { v[c] = xb[(64 + c) * 4096 + l]; ss += v[c] * v[c]; }
        float inv = 1.f / fmaxf(sqrtf(ss), 1e-4f);
        uint4 lq[8], kq[8];
        #pragma unroll
        for (int c8 = 0; c8 < 8; ++c8) {
            u32 wl[4], wk[4];
            #pragma unroll
            for (int i = 0; i < 4; ++i) {
                float a = v[c8 * 8 + 2 * i], bb2 = v[c8 * 8 + 2 * i + 1];
                wl[i] = (u32)f2bf(a) | ((u32)f2bf(bb2) << 16);
                wk[i] = (u32)f2bf(a * inv) | ((u32)f2bf(bb2 * inv) << 16);
            }
            lq[c8] = make_uint4(wl[0], wl[1], wl[2], wl[3]);
            kq[c8] = make_uint4(wk[0], wk[1], wk[2], wk[3]);
        }
        u16* lr = latb + (size_t)(b * 4096 + l) * 64;
        #pragma unroll
        for (int c8 = 0; c8 < 8; ++c8) *(uint4*)(lr + c8 * 8) = lq[c8];
        // garr scatter: this knorm row l feeds garr[sg=T(l+1-aa)+1][aa]
        #pragma unroll
        for (int aa = 0; aa < 3; ++aa) {
            int src = l + 1 - aa;
            if (src >= 0 && src < L) {
                int sg = (((src & 63) << 6) | (src >> 6)) + 1;
                char* dst = garr + (size_t)b * GARR_BB + (size_t)sg * 384;
                int key = (sg & 7) << 4;
                #pragma unroll
                for (int c8 = 0; c8 < 8; ++c8)
                    *(uint4*)(dst + ((aa * 128 + c8 * 16) ^ key)) = kq[c8];
            }
        }
        u16* fr = forb + (size_t)(b * 4096 + l) * 64;
        #pragma unroll
        for (int c8 = 0; c8 < 8; ++c8) {
            u32 wf[4];
            #pragma unroll
            for (int i = 0; i < 4; ++i) {
                float a = xb[(c8 * 8 + 2 * i) * 4096 + l];
                float bb2 = xb[(c8 * 8 + 2 * i + 1) * 4096 + l];
                wf[i] = (u32)f2bf(a) | ((u32)f2bf(bb2) << 16);
            }
            *(uint4*)(fr + c8 * 8) = make_uint4(wf[0], wf[1], wf[2], wf[3]);
        }
    } else {                                // compact + zero done + garr patches
        __shared__ int lcnt;
        __shared__ u32 lb[128];
        if (t == 0) lcnt = 0;
        if (t < 128) lb[t] = 0u;
        __syncthreads();
        for (int i = t; i < L; i += 256) {
            if (mask[i] > 0.5f) {
                int p = atomicAdd(&lcnt, 1);
                if (p < 2048) rows[p] = i;
                int kp = ((i & 63) << 6) | (i >> 6);
                atomicOr(&lb[kp >> 5], 1u << (kp & 31));
            }
        }
        __syncthreads();
        if (t < 128) fbits[t] = lb[t];
        if (t == 0) cnt[0] = min(lcnt, 2048);
        if (t < 128) done[t] = 0u;
        // zero never-written garr regions (ws is poisoned each call):
        // per b: slot0 (384B), slot4097 (384B), sg=1 bytes[0,128), sg=4096 bytes[256,384)
        if (t < 128) {
            int b = t >> 6, i = t & 63;
            char* gB = garr + (size_t)b * GARR_BB;
            uint4 z = make_uint4(0, 0, 0, 0);
            if (i < 24)       *(uint4*)(gB + i * 16) = z;
            else if (i < 48)  *(uint4*)(gB + (size_t)4097 * 384 + (i - 24) * 16) = z;
            else if (i < 56)  *(uint4*)(gB + (size_t)1 * 384 + (i - 48) * 16) = z;
            else              *(uint4*)(gB + (size_t)4096 * 384 + 256 + (i - 56) * 16) = z;
        }
    }
}

// ---------------- main flash kernel (+ fused ks reduction) ----------------
// LDS (80000 B, 2 blocks/CU): slab 52224 | F_s 17408 | p_s 10240 | rl_s 128
__global__ __launch_bounds__(256, 2)
void k_flash(const u16* __restrict__ latb, const u16* __restrict__ forb,
             const char* __restrict__ garr, const u32* __restrict__ fbits,
             const int* __restrict__ rows, const int* __restrict__ cnt,
             char* __restrict__ part, u32* __restrict__ done,
             float* __restrict__ out)
{
    __shared__ __align__(16) char smem[80000];
    char* slab = smem;
    u16*  F_s  = (u16*)(smem + 52224);
    u16*  p_s  = (u16*)(smem + 69632);
    int*  rl_s = (int*)(smem + 79872);

    // XCD-aware decode: each XCD owns 2 (ks,b) slab groups
    const int lin = blockIdx.x;             // [0,1024)
    const int xcd = lin & 7, slotq = lin >> 3;
    const int gid = xcd * 128 + slotq;
    const int ksb = gid >> 6, rt = gid & 63;
    const int ks = ksb >> 1, b = ksb & 1;

    const int t = threadIdx.x;
    const int count = cnt[0];
    const int base = rt * 32;
    if (base >= count) return;
    const int nact = min(32, count - base);
    if (t < 32) rl_s[t] = rows[base + min(t, nact - 1)];
    __syncthreads();

    const int l = t & 63, w = t >> 6;
    const int li = l & 31, hi = l >> 5;
    const size_t boff = (size_t)b * 262144;

    // ---- U gather into NAMED registers, pinned via direct "+v" asm ----
    const u16* zp = (const u16*)garr;       // slot 0 = zeros
    int gl = rl_s[li];
    int tl0 = ((gl & 63) << 6) | (gl >> 6);
    const u16* rp[9];
    #pragma unroll
    for (int tap = 0; tap < 9; ++tap) {
        int bb = tap / 3, aa = tap - 3 * (tap / 3);
        int mp = tl0 + bb - 1;
        const u16* p = zp;
        if (mp >= 0 && mp < L) {
            int q = (((mp & 63) << 6) | (mp >> 6)) + aa - 1;
            if (q >= 0 && q < L) p = latb + boff + (size_t)q * 64;
        }
        rp[tap] = p;
    }
#define DECL_BU(TAP) \
    short8 bu##TAP##_0 = *(const short8*)(rp[TAP] + 0  + hi * 8); \
    short8 bu##TAP##_1 = *(const short8*)(rp[TAP] + 16 + hi * 8); \
    short8 bu##TAP##_2 = *(const short8*)(rp[TAP] + 32 + hi * 8); \
    short8 bu##TAP##_3 = *(const short8*)(rp[TAP] + 48 + hi * 8); \
    asm volatile("" : "+v"(bu##TAP##_0), "+v"(bu##TAP##_1), "+v"(bu##TAP##_2), "+v"(bu##TAP##_3));
    DECL_BU(0) DECL_BU(1) DECL_BU(2) DECL_BU(3) DECL_BU(4)
    DECL_BU(5) DECL_BU(6) DECL_BU(7) DECL_BU(8)
#undef DECL_BU

    float mrun = -INFINITY, srun = 0.f;
    f32x16 acc0, acc1;
    #pragma unroll
    for (int r = 0; r < 16; ++r) { acc0[r] = 0.f; acc1[r] = 0.f; }

    const int kp0 = ks * 512;
    const char* gb = garr + (size_t)b * GARR_BB;
    uint4 fA0, fA1, fB0, fB1;

    auto issue_slab = [&](int k0p) {
        const char* gw = gb + (size_t)k0p * 384;
        #pragma unroll
        for (int i = 0; i < 13; ++i) {
            int idx = w + 4 * i;
            if (idx < 51) lds_async16(slab + idx * 1024, gw + idx * 1024 + l * 16);
        }
    };
    auto issue_F = [&](int k0p) {
        int kpA = k0p + 2 * l, kpB = kpA + 1;
        int kA = ((kpA & 63) << 6) | (kpA >> 6);
        int kB = ((kpB & 63) << 6) | (kpB >> 6);
        const u32* pa = (const u32*)(forb + boff + (size_t)kA * 64 + w * 16);
        const u32* pc = (const u32*)(forb + boff + (size_t)kB * 64 + w * 16);
        fA0 = *(const uint4*)pa; fA1 = *(const uint4*)(pa + 4);
        fB0 = *(const uint4*)pc; fB1 = *(const uint4*)(pc + 4);
    };
    auto write_F = [&]() {
        u32 av[8] = {fA0.x, fA0.y, fA0.z, fA0.w, fA1.x, fA1.y, fA1.z, fA1.w};
        u32 bv[8] = {fB0.x, fB0.y, fB0.z, fB0.w, fB1.x, fB1.y, fB1.z, fB1.w};
        #pragma unroll
        for (int i2 = 0; i2 < 8; ++i2) {
            u32 w0 = (av[i2] & 0xffffu) | (bv[i2] << 16);
            u32 w1 = (av[i2] >> 16) | (bv[i2] & 0xffff0000u);
            *(u32*)((char*)F_s + (w * 16 + 2 * i2) * 272 + l * 4) = w0;
            *(u32*)((char*)F_s + (w * 16 + 2 * i2 + 1) * 272 + l * 4) = w1;
        }
    };

    // prologue
    issue_slab(kp0);
    issue_F(kp0);
    asm volatile("s_waitcnt vmcnt(0)" ::: "memory");
    write_F();
    __syncthreads();

    for (int kt = 0; kt < 4; ++kt) {
        const int k0p = kp0 + kt * 128;

        // ---- score: S^T tile (M=32 k'cols, N=32 rows), K=576 ----
        f32x16 sc;
        #pragma unroll
        for (int r = 0; r < 16; ++r) sc[r] = 0.f;
        const int slot_base = w * 32 + li;
        __builtin_amdgcn_s_setprio(1);
#define TAP_MFMA(TAP) do { \
        const int bb = TAP / 3, aac = TAP % 3; \
        int sl = slot_base + bb; \
        int key = (sl & 7) << 4; \
        int base_b = sl * 384 + aac * 128 + hi * 16; \
        sc = MFMA32(*(const short8*)(slab + ((base_b +  0) ^ key)), bu##TAP##_0, sc); \
        sc = MFMA32(*(const short8*)(slab + ((base_b + 32) ^ key)), bu##TAP##_1, sc); \
        sc = MFMA32(*(const short8*)(slab + ((base_b + 64) ^ key)), bu##TAP##_2, sc); \
        sc = MFMA32(*(const short8*)(slab + ((base_b + 96) ^ key)), bu##TAP##_3, sc); \
    } while (0)
        TAP_MFMA(0); TAP_MFMA(1); TAP_MFMA(2); TAP_MFMA(3); TAP_MFMA(4);
        TAP_MFMA(5); TAP_MFMA(6); TAP_MFMA(7); TAP_MFMA(8);
#undef TAP_MFMA
        __builtin_amdgcn_s_setprio(0);
        __syncthreads();                   // all waves done reading slab(kt)

        if (kt < 3) { issue_slab(k0p + 128); issue_F(k0p + 128); }

        // ---- mask + online softmax (lane-local row li) ----
        u32 bits = fbits[(k0p >> 5) + w];
        float sv[16]; float mx = -INFINITY;
        #pragma unroll
        for (int r = 0; r < 16; ++r) {
            int kloc = (r & 3) + 8 * (r >> 2) + 4 * hi;
            float s = sc[r];
            if ((bits >> kloc) & 1) s = -INFINITY;
            sv[r] = s; mx = fmaxf(mx, s);
        }
        mx = fmaxf(mx, __shfl_xor(mx, 32, 64));
        float newm = fmaxf(mrun, mx);
        float fac, tsum = 0.f;
        u16 pb[16];
        if (newm > -INFINITY) {
            fac = __expf(mrun - newm);
            #pragma unroll
            for (int r = 0; r < 16; ++r) { float p = __expf(sv[r] - newm); tsum += p; pb[r] = f2bf(p); }
        } else {
            fac = 1.f;
            #pragma unroll
            for (int r = 0; r < 16; ++r) pb[r] = 0;
        }
        tsum += __shfl_xor(tsum, 32, 64);
        srun = srun * fac + tsum;
        mrun = newm;
        #pragma unroll
        for (int rq = 0; rq < 8; ++rq) {
            int r = rq * 2;
            int kloc = (r & 3) + 8 * (r >> 2) + 4 * hi;
            u32 pw = (u32)pb[r] | ((u32)pb[r + 1] << 16);
            *(u32*)(p_s + w * 1280 + li * 40 + kloc) = pw;
        }

        // ---- rescale acc, PV ----
        #pragma unroll
        for (int r = 0; r < 16; ++r) {
            int row = (r & 3) + 8 * (r >> 2) + 4 * hi;
            float fr = __shfl(fac, row, 64);
            acc0[r] *= fr; acc1[r] *= fr;
        }
        #pragma unroll
        for (int Ksi2 = 0; Ksi2 < 2; ++Ksi2) {
            short8 pa2 = *(const short8*)(p_s + w * 1280 + li * 40 + Ksi2 * 16 + hi * 8);
            short8 f0 = *(const short8*)(F_s + li * 136 + w * 32 + Ksi2 * 16 + hi * 8);
            short8 f1 = *(const short8*)(F_s + (32 + li) * 136 + w * 32 + Ksi2 * 16 + hi * 8);
            acc0 = MFMA32(pa2, f0, acc0);
            acc1 = MFMA32(pa2, f1, acc1);
        }
        __syncthreads();                   // all waves done reading F_s(kt)

        if (kt < 3) {
            asm volatile("s_waitcnt vmcnt(0)" ::: "memory");
            write_F();
        }
        __syncthreads();                   // F_s(kt+1) + slab(kt+1) ready
    }

    // ---- merge 4 waves (um aliases slab), write bf16 partials ----
    float* um = (float*)smem;   // [4][32][66]
    if (l < 32) { um[(w * 32 + li) * 66] = mrun; um[(w * 32 + li) * 66 + 1] = srun; }
    #pragma unroll
    for (int r = 0; r < 16; ++r) {
        int row = (r & 3) + 8 * (r >> 2) + 4 * hi;
        um[(w * 32 + row) * 66 + 2 + li] = acc0[r];
        um[(w * 32 + row) * 66 + 2 + 32 + li] = acc1[r];
    }
    __syncthreads();
    {
        int row = t >> 3, cq = t & 7;
        float m4[4], s4[4];
        #pragma unroll
        for (int wv = 0; wv < 4; ++wv) {
            m4[wv] = um[(wv * 32 + row) * 66];
            s4[wv] = um[(wv * 32 + row) * 66 + 1];
        }
        float M = fmaxf(fmaxf(m4[0], m4[1]), fmaxf(m4[2], m4[3]));
        float S = 0.f; float wx[4];
        if (M > -INFINITY) {
            #pragma unroll
            for (int wv = 0; wv < 4; ++wv) { wx[wv] = __expf(m4[wv] - M); S += s4[wv] * wx[wv]; }
        } else {
            wx[0] = wx[1] = wx[2] = wx[3] = 0.f;
        }
        char* pp = part + ((size_t)((b * 64 + rt) * 8 + ks)) * 4608 + row * 144;
        u16 h[8];
        #pragma unroll
        for (int i = 0; i < 8; ++i) {
            int ch = cq * 8 + i;
            float vv = 0.f;
            #pragma unroll
            for (int wv = 0; wv < 4; ++wv) vv += wx[wv] * um[(wv * 32 + row) * 66 + 2 + ch];
            h[i] = f2bf(vv);
        }
        if (cq == 0) { *(float*)pp = M; *(float*)(pp + 4) = S; }
        uint4 hw;
        hw.x = (u32)h[0] | ((u32)h[1] << 16); hw.y = (u32)h[2] | ((u32)h[3] << 16);
        hw.z = (u32)h[4] | ((u32)h[5] << 16); hw.w = (u32)h[6] | ((u32)h[7] << 16);
        *(uint4*)(pp + 16 + cq * 16) = hw;
    }

    // ---- fan-in: last of 8 ks blocks reduces and writes shift ----
    __threadfence();
    __syncthreads();
    if (t == 0) rl_s[0] = (atomicAdd(&done[b * 64 + rt], 1u) == 7u) ? 1 : 0;
    __syncthreads();
    if (!rl_s[0]) return;
    __threadfence();
    {
        int row = t >> 3, cq = t & 7;
        int slot = base + row;
        if (slot < count) {
            int lr = rows[slot];
            const char* pbp = part + ((size_t)((b * 64 + rt) * 8)) * 4608 + row * 144;
            float M = -INFINITY, m8[8], s8[8];
            #pragma unroll
            for (int k = 0; k < 8; ++k) {
                m8[k] = *(const float*)(pbp + k * 4608);
                s8[k] = *(const float*)(pbp + k * 4608 + 4);
                M = fmaxf(M, m8[k]);
            }
            if (M > -INFINITY) {
                float S = 0.f; float accv[8] = {0.f,0.f,0.f,0.f,0.f,0.f,0.f,0.f};
                #pragma unroll
                for (int k = 0; k < 8; ++k) {
                    float wxv = __expf(m8[k] - M);
                    S += s8[k] * wxv;
                    uint4 hv = *(const uint4*)(pbp + k * 4608 + 16 + cq * 16);
                    u32 uu[4] = {hv.x, hv.y, hv.z, hv.w};
                    #pragma unroll
                    for (int i = 0; i < 4; ++i) {
                        accv[2 * i]     += wxv * __uint_as_float((uu[i] & 0xffffu) << 16);
                        accv[2 * i + 1] += wxv * __uint_as_float(uu[i] & 0xffff0000u);
                    }
                }
                float invS = (S > 0.f) ? 1.f / S : 0.f;
                float* ob = out + (size_t)b * 786432 + 524288 + lr;
                #pragma unroll
                for (int i = 0; i < 8; ++i) ob[(size_t)(cq * 8 + i) * 4096] = accv[i] * invS;
            }
        }
    }
}

extern "C" void kernel_launch(void* const* d_in, const int* in_sizes, int n_in,
                              void* d_out, int out_size, void* d_ws, size_t ws_size,
                              hipStream_t stream)
{
    const float* x    = (const float*)d_in[0];
    const float* mask = (const float*)d_in[1];
    float* out = (float*)d_out;
    char* ws = (char*)d_ws;

    u16* latb  = (u16*)(ws + OFF_LATB);
    u16* forb  = (u16*)(ws + OFF_FORB);
    char* garr = ws + OFF_GARR;
    u32* fbits = (u32*)(ws + OFF_FBITS);
    int* rows  = (int*)(ws + OFF_ROWS);
    int* cnt   = (int*)(ws + OFF_CNT);
    u32* done  = (u32*)(ws + OFF_DONE);
    char* part = ws + OFF_PART;

    k_pre1<<<1570, 256, 0, stream>>>((const float4*)x, (float4*)out, x, mask,
                                     latb, forb, garr, rows, cnt, fbits, done);
    k_flash<<<1024, 256, 0, stream>>>(latb, forb, garr, fbits, rows, cnt, part, done, out);
}